// Round 5
// baseline (236.152 us; speedup 1.0000x reference)
//
#include <hip/hip_runtime.h>

#define GN   1024
#define GNN  (GN * GN)
#define GP   16
#define NOUT 127          // ys[1:] = T_1 .. T_127
#define TILE 64           // output tile per block
#define KST  8            // fused time steps per launch
#define SZ   80           // TILE + 2*KST (region side)
#define NRS  20           // strips per row = SZ/4
#define NSTR 1600         // SZ * NRS
#define NTHR 1024
#define NM   2            // strip passes per thread

// Exact fp32 constants: DT/dx^2 = 1e-7*1023^2 = 0.1046529, DT/(2dx) = 5.115e-5

__device__ __forceinline__ void coord16(int t, int& c0, int& c1, float& w) {
    // coords = linspace(0, 15, 1024): c = t * 15/1023
    double c = (double)t * (15.0 / 1023.0);
    c0 = (int)c;
    c1 = c0 + 1 > 15 ? 15 : c0 + 1;
    w  = (float)(c - (double)c0);
}

__device__ __forceinline__ float bilin16(const float* __restrict__ m,
                                         int i0, int i1, float wi,
                                         int j0, int j1, float wj) {
    float m00 = m[i0 * GP + j0];
    float m10 = m[i1 * GP + j0];
    float m01 = m[i0 * GP + j1];
    float m11 = m[i1 * GP + j1];
    float r0 = m00 * (1.0f - wi) + m10 * wi;
    float r1 = m01 * (1.0f - wi) + m11 * wi;
    return r0 * (1.0f - wj) + r1 * wj;
}

__device__ __forceinline__ float cellv(float C, float L, float R, float U, float D,
                                       float a2, float k2) {
    // val = C - k2*C*((D-U)+(R-L)) + a2*(U+D+L+R-4C)
    float s   = (D - U) + (R - L);
    float lap = fmaf(-4.0f, C, (U + D) + (L + R));
    return fmaf(a2, lap, fmaf(-k2, C * s, C));
}

// LDS-only barrier: waits DS ops, lets global stores stay in flight
// (__syncthreads would drain vmcnt(0), serializing the slab stores with the
// step loop — the m97 barrier-drain stall). "memory" clobbers + sched_barrier
// pin ordering at the compiler level (rule #18).
__device__ __forceinline__ void lds_barrier() {
    __builtin_amdgcn_sched_barrier(0);
    asm volatile("s_waitcnt lgkmcnt(0)" ::: "memory");
    __builtin_amdgcn_s_barrier();
    __builtin_amdgcn_sched_barrier(0);
}

// Precompute clamp-baked, pre-scaled coefficient maps into workspace:
//   a2map[i*GN+j] = bilin(alpha at clamp(i),clamp(j)) * DT/dx^2
//   k2map[i*GN+j] = bilin(kappa at clamp(i),clamp(j)) * DT/(2dx)
__global__ __launch_bounds__(256)
void resize_maps_kernel(const float* __restrict__ alpha,
                        const float* __restrict__ kappa,
                        float* __restrict__ a2map,
                        float* __restrict__ k2map) {
    int idx = blockIdx.x * 256 + threadIdx.x;
    if (idx >= GNN) return;
    int i = idx >> 10;
    int j = idx & (GN - 1);
    int ci = i < 1 ? 1 : (i > GN - 2 ? GN - 2 : i);
    int cj = j < 1 ? 1 : (j > GN - 2 ? GN - 2 : j);
    int i0, i1, j0, j1; float wi, wj;
    coord16(ci, i0, i1, wi);
    coord16(cj, j0, j1, wj);
    a2map[idx] = bilin16(alpha, i0, i1, wi, j0, j1, wj) * 0.1046529f;
    k2map[idx] = bilin16(kappa, i0, i1, wi, j0, j1, wj) * 5.115e-5f;
}

// Temporal-blocked stepper, stale-halo scheme (see round-4 comments).
// Register carry V[m] holds the CLAMPED row's values — at physical top/bottom
// rows this makes the boundary strip operand-identical to its interior
// neighbor (exact boundary replication by induction). Interior region edges
// are stale-tolerated: contamination advances <=1 cell/step, core sits behind
// an 8-deep halo, 8 steps per launch.
template <bool USE_WS>
__global__ __launch_bounds__(NTHR)
void fused_steps_kernel(const float* __restrict__ src,
                        const float* __restrict__ Aarg,   // a2map (full) or alpha (16x16)
                        const float* __restrict__ Karg,   // k2map (full) or kappa (16x16)
                        float* __restrict__ out,
                        int base, int kk)
{
    __shared__ float buf[2][SZ * SZ];   // 2 x 25.6 KB

    const int tid = threadIdx.x;
    const int gi0 = blockIdx.y * TILE;
    const int gj0 = blockIdx.x * TILE;
    int oi = gi0 - KST; oi = oi < 0 ? 0 : (oi > GN - SZ ? GN - SZ : oi);
    int oj = gj0 - KST; oj = oj < 0 ? 0 : (oj > GN - SZ ? GN - SZ : oj);
    const int di = gi0 - oi;            // core row offset in region (0, 8, or 16)
    const int dj = gj0 - oj;

    bool  act[NM], isl[NM], isr[NM], core[NM];
    int   voff[NM], upoff[NM], dnoff[NM], sloff[NM], sroff[NM], goff[NM], cgoff[NM];
    float a2[NM][4], k2[NM][4];
    float4 V[NM];

    #pragma unroll
    for (int m = 0; m < NM; ++m) {
        int s = tid + m * NTHR;
        act[m] = (s < NSTR);
        int ss = act[m] ? s : 0;
        int r = ss / NRS, c = ss % NRS;
        int gi = oi + r;
        int cig = gi < 1 ? 1 : (gi > GN - 2 ? GN - 2 : gi);
        int ai = cig - oi; ai = ai < 1 ? 1 : (ai > SZ - 2 ? SZ - 2 : ai);
        isl[m] = (c == 0);
        isr[m] = (c == NRS - 1);
        voff[m]  = r * SZ + 4 * c;
        upoff[m] = (ai - 1) * SZ + 4 * c;
        dnoff[m] = (ai + 1) * SZ + 4 * c;
        sloff[m] = ai * SZ + (isl[m] ? 0      : 4 * c - 1);
        sroff[m] = ai * SZ + (isr[m] ? SZ - 1 : 4 * c + 4);
        goff[m]  = gi  * GN + oj + 4 * c;
        cgoff[m] = cig * GN + oj + 4 * c;   // clamped-row addr (carry + coeffs)
        core[m]  = act[m] && r >= di && r < di + TILE
                          && c >= (dj >> 2) && c < (dj >> 2) + 16;
        if (USE_WS) {
            if (act[m]) {
                float4 a = *(const float4*)(Aarg + cgoff[m]);
                float4 k = *(const float4*)(Karg + cgoff[m]);
                a2[m][0] = a.x; a2[m][1] = a.y; a2[m][2] = a.z; a2[m][3] = a.w;
                k2[m][0] = k.x; k2[m][1] = k.y; k2[m][2] = k.z; k2[m][3] = k.w;
            }
        } else {
            int i0, i1; float wi;
            coord16(cig, i0, i1, wi);
            #pragma unroll
            for (int u = 0; u < 4; ++u) {
                int gj = oj + 4 * c + u;
                int cjg = gj < 1 ? 1 : (gj > GN - 2 ? GN - 2 : gj);
                int j0, j1; float wj;
                coord16(cjg, j0, j1, wj);
                a2[m][u] = bilin16(Aarg, i0, i1, wi, j0, j1, wj) * 0.1046529f;
                k2[m][u] = bilin16(Karg, i0, i1, wi, j0, j1, wj) * 5.115e-5f;
            }
        }
    }

    // Initial load: LDS gets the strip's own row; V gets the CLAMPED row.
    #pragma unroll
    for (int m = 0; m < NM; ++m) {
        if (act[m]) {
            float4 ld = *(const float4*)(src + goff[m]);
            *(float4*)&buf[0][voff[m]] = ld;
            V[m] = (cgoff[m] == goff[m]) ? ld
                                         : *(const float4*)(src + cgoff[m]);
        }
    }
    __syncthreads();   // once per launch; global loads need draining anyway

    int p = 0;
    for (int t = 1; t <= kk; ++t) {
        const float* __restrict__ cur = buf[p];
        float* __restrict__ nxt = buf[p ^ 1];
        float* __restrict__ slab = out + (long)(base + t - 1) * GNN;

        #pragma unroll
        for (int m = 0; m < NM; ++m) {
            if (act[m]) {
                float4 U = *(const float4*)(cur + upoff[m]);
                float4 D = *(const float4*)(cur + dnoff[m]);
                float sl = cur[sloff[m]];
                float sr = cur[sroff[m]];
                float v0 = V[m].x, v1 = V[m].y, v2 = V[m].z, v3 = V[m].w;

                // Edge-cell operand selection (boundary-replicated clamped centers)
                float L0 = isl[m] ? v0  : sl;
                float C0 = isl[m] ? v1  : v0;
                float R0 = isl[m] ? v2  : v1;
                float U0 = isl[m] ? U.y : U.x;
                float D0 = isl[m] ? D.y : D.x;
                float L3 = isr[m] ? v1  : v2;
                float C3 = isr[m] ? v2  : v3;
                float R3 = isr[m] ? v3  : sr;
                float U3 = isr[m] ? U.z : U.w;
                float D3 = isr[m] ? D.z : D.w;

                float4 NV;
                NV.x = cellv(C0, L0, R0, U0, D0, a2[m][0], k2[m][0]);
                NV.y = cellv(v1, v0, v2, U.y, D.y, a2[m][1], k2[m][1]);
                NV.z = cellv(v2, v1, v3, U.z, D.z, a2[m][2], k2[m][2]);
                NV.w = cellv(C3, L3, R3, U3, D3, a2[m][3], k2[m][3]);

                *(float4*)(nxt + voff[m]) = NV;
                if (core[m]) *(float4*)(slab + goff[m]) = NV;
                V[m] = NV;
            }
        }
        lds_barrier();   // DS-only wait: global stores keep draining async
        p ^= 1;
    }
}

extern "C" void kernel_launch(void* const* d_in, const int* in_sizes, int n_in,
                              void* d_out, int out_size, void* d_ws, size_t ws_size,
                              hipStream_t stream) {
    const float* u0    = (const float*)d_in[0];
    const float* alpha = (const float*)d_in[1];
    const float* kappa = (const float*)d_in[2];
    float* out = (float*)d_out;

    dim3 grd(GN / TILE, GN / TILE, 1);   // 16x16 = 256 blocks = 1/CU

    bool use_ws = ws_size >= (size_t)2 * GNN * sizeof(float);

    if (use_ws) {
        float* a2map = (float*)d_ws;
        float* k2map = a2map + GNN;
        resize_maps_kernel<<<(GNN + 255) / 256, 256, 0, stream>>>(alpha, kappa, a2map, k2map);
        for (int b = 0; b < NOUT; b += KST) {
            int kk = NOUT - b; if (kk > KST) kk = KST;
            const float* src = (b == 0) ? u0 : out + (long)(b - 1) * GNN;
            fused_steps_kernel<true><<<grd, NTHR, 0, stream>>>(src, a2map, k2map, out, b, kk);
        }
    } else {
        for (int b = 0; b < NOUT; b += KST) {
            int kk = NOUT - b; if (kk > KST) kk = KST;
            const float* src = (b == 0) ? u0 : out + (long)(b - 1) * GNN;
            fused_steps_kernel<false><<<grd, NTHR, 0, stream>>>(src, alpha, kappa, out, b, kk);
        }
    }
}

// Round 6
// 210.506 us; speedup vs baseline: 1.1218x; 1.1218x over previous
//
#include <hip/hip_runtime.h>

#define GN   1024
#define GNN  (GN * GN)
#define GP   16
#define NOUT 127          // ys[1:] = T_1 .. T_127
#define TILE 64           // output tile per block
#define KST  16           // fused time steps per launch
#define SZ   96           // TILE + 2*KST (region side)
#define LSTR 100          // padded LDS row stride (floats); 400B -> +16B bank rot / row-block
#define NRB  24           // row-blocks  (SZ/4)
#define NCB  24           // col-blocks  (SZ/4)
#define NTHR 576          // NRB*NCB threads, 9 waves

// Exact fp32 constants: DT/dx^2 = 1e-7*1023^2 = 0.1046529, DT/(2dx) = 5.115e-5

__device__ __forceinline__ void coord16(int t, int& c0, int& c1, float& w) {
    // coords = linspace(0, 15, 1024): c = t * 15/1023
    double c = (double)t * (15.0 / 1023.0);
    c0 = (int)c;
    c1 = c0 + 1 > 15 ? 15 : c0 + 1;
    w  = (float)(c - (double)c0);
}

__device__ __forceinline__ float bilin16(const float* __restrict__ m,
                                         int i0, int i1, float wi,
                                         int j0, int j1, float wj) {
    float m00 = m[i0 * GP + j0];
    float m10 = m[i1 * GP + j0];
    float m01 = m[i0 * GP + j1];
    float m11 = m[i1 * GP + j1];
    float r0 = m00 * (1.0f - wi) + m10 * wi;
    float r1 = m01 * (1.0f - wi) + m11 * wi;
    return r0 * (1.0f - wj) + r1 * wj;
}

__device__ __forceinline__ float cellv(float C, float L, float R, float U, float D,
                                       float a2, float k2) {
    // val = C - k2*C*((D-U)+(R-L)) + a2*(U+D+L+R-4C)
    float s   = (D - U) + (R - L);
    float lap = fmaf(-4.0f, C, (U + D) + (L + R));
    return fmaf(a2, lap, fmaf(-k2, C * s, C));
}

// One 4-wide row of cells: verified column shift-select logic (round 4).
// v = clamped-row center carry; U/D = up/down operand rows (same 4 cols);
// sl/sr = left/right LDS scalars.
__device__ __forceinline__ float4 rowcell(float4 v, float4 U, float4 D,
                                          float sl, float sr,
                                          float4 a2, float4 k2,
                                          bool isl, bool isr) {
    float L0 = isl ? v.x : sl;
    float C0 = isl ? v.y : v.x;
    float R0 = isl ? v.z : v.y;
    float U0 = isl ? U.y : U.x;
    float D0 = isl ? D.y : D.x;
    float L3 = isr ? v.y : v.z;
    float C3 = isr ? v.z : v.w;
    float R3 = isr ? v.w : sr;
    float U3 = isr ? U.z : U.w;
    float D3 = isr ? D.z : D.w;
    float4 nv;
    nv.x = cellv(C0,  L0,  R0,  U0,  D0,  a2.x, k2.x);
    nv.y = cellv(v.y, v.x, v.z, U.y, D.y, a2.y, k2.y);
    nv.z = cellv(v.z, v.y, v.w, U.z, D.z, a2.z, k2.z);
    nv.w = cellv(C3,  L3,  R3,  U3,  D3,  a2.w, k2.w);
    return nv;
}

// LDS-only barrier (global stores stay in flight; rule #18 fencing).
__device__ __forceinline__ void lds_barrier() {
    __builtin_amdgcn_sched_barrier(0);
    asm volatile("s_waitcnt lgkmcnt(0)" ::: "memory");
    __builtin_amdgcn_s_barrier();
    __builtin_amdgcn_sched_barrier(0);
}

// Clamp-baked, pre-scaled coefficient maps:
//   a2map[i*GN+j] = bilin(alpha at clamp(i),clamp(j)) * DT/dx^2
//   k2map[i*GN+j] = bilin(kappa at clamp(i),clamp(j)) * DT/(2dx)
__global__ __launch_bounds__(256)
void resize_maps_kernel(const float* __restrict__ alpha,
                        const float* __restrict__ kappa,
                        float* __restrict__ a2map,
                        float* __restrict__ k2map) {
    int idx = blockIdx.x * 256 + threadIdx.x;
    if (idx >= GNN) return;
    int i = idx >> 10;
    int j = idx & (GN - 1);
    int ci = i < 1 ? 1 : (i > GN - 2 ? GN - 2 : i);
    int cj = j < 1 ? 1 : (j > GN - 2 ? GN - 2 : j);
    int i0, i1, j0, j1; float wi, wj;
    coord16(ci, i0, i1, wi);
    coord16(cj, j0, j1, wj);
    a2map[idx] = bilin16(alpha, i0, i1, wi, j0, j1, wj) * 0.1046529f;
    k2map[idx] = bilin16(kappa, i0, i1, wi, j0, j1, wj) * 5.115e-5f;
}

// Temporal-blocked stepper, stale-halo scheme, 4x4 cells/thread.
// Row-block 0 / NRB-1 are universal replica rows (== the verified ai-clamp
// semantics): at physical edges they ARE the exact boundary replication; at
// interior region edges they are stale-tolerated halo (contamination moves
// 1 row/step; core sits KST=16 rows in). Register carry V[q] holds the
// clamped row's values; columns use the verified shift-select logic.
template <bool USE_WS>
__global__ __launch_bounds__(NTHR)
void fused_steps_kernel(const float* __restrict__ srcp,
                        const float* __restrict__ Aarg,   // a2map or alpha
                        const float* __restrict__ Karg,   // k2map or kappa
                        float* __restrict__ out,
                        int base)
{
    __shared__ float buf[2][SZ * LSTR];   // 2 x 38.4 KB

    const int tid = threadIdx.x;
    const int rb  = tid / NCB;
    const int cb  = tid - rb * NCB;
    const int r0  = rb * 4;
    const int c4  = cb * 4;

    const int gi0 = blockIdx.y * TILE;
    const int gj0 = blockIdx.x * TILE;
    int oi = gi0 - KST; oi = oi < 0 ? 0 : (oi > GN - SZ ? GN - SZ : oi);
    int oj = gj0 - KST; oj = oj < 0 ? 0 : (oj > GN - SZ ? GN - SZ : oj);
    const int di = gi0 - oi;            // 0, 16, or 32 (multiples of 4)
    const int dj = gj0 - oj;

    const bool istop = (rb == 0), isbot = (rb == NRB - 1);
    const bool isl   = (cb == 0), isr   = (cb == NCB - 1);
    const bool core  = (rb >= (di >> 2)) && (rb < (di >> 2) + 16)
                    && (cb >= (dj >> 2)) && (cb < (dj >> 2) + 16);
    const int  tmax  = NOUT - base;     // steps with t<=tmax store output

    const long gbase = (long)(oi + r0) * GN + oj + c4;

    // LDS float-index bases
    const int ob  = r0 * LSTR + c4;                        // own 4 rows
    const int ub  = (istop ? 0 : (r0 - 1)) * LSTR + c4;    // up-halo row
    const int db  = (isbot ? (SZ - 1) : (r0 + 4)) * LSTR + c4;  // down-halo row
    const int slo = r0 * LSTR + (isl ? 0 : (c4 - 1));      // left scalars (+q*LSTR)
    const int sro = r0 * LSTR + (isr ? (SZ - 1) : (c4 + 4));

    // Coefficients for own 4 rows (replica rows' coeffs unused -> any value ok)
    float4 a2[4], k2[4];
    if (USE_WS) {
        #pragma unroll
        for (int q = 0; q < 4; ++q) {
            a2[q] = *(const float4*)(Aarg + gbase + q * GN);
            k2[q] = *(const float4*)(Karg + gbase + q * GN);
        }
    } else {
        #pragma unroll
        for (int q = 0; q < 4; ++q) {
            int gi = oi + r0 + q;
            int ci = gi < 1 ? 1 : (gi > GN - 2 ? GN - 2 : gi);
            int i0, i1; float wi;
            coord16(ci, i0, i1, wi);
            float av[4], kv[4];
            #pragma unroll
            for (int u = 0; u < 4; ++u) {
                int gj = oj + c4 + u;
                int cj = gj < 1 ? 1 : (gj > GN - 2 ? GN - 2 : gj);
                int j0, j1; float wj;
                coord16(cj, j0, j1, wj);
                av[u] = bilin16(Aarg, i0, i1, wi, j0, j1, wj) * 0.1046529f;
                kv[u] = bilin16(Karg, i0, i1, wi, j0, j1, wj) * 5.115e-5f;
            }
            a2[q] = make_float4(av[0], av[1], av[2], av[3]);
            k2[q] = make_float4(kv[0], kv[1], kv[2], kv[3]);
        }
    }

    // Initial load: LDS gets raw own rows; V carries the clamped rows
    // (replica row-blocks reuse the adjacent genuine row's load).
    float4 V[4];
    {
        float4 ld0 = *(const float4*)(srcp + gbase);
        float4 ld1 = *(const float4*)(srcp + gbase + GN);
        float4 ld2 = *(const float4*)(srcp + gbase + 2 * GN);
        float4 ld3 = *(const float4*)(srcp + gbase + 3 * GN);
        *(float4*)&buf[0][ob]            = ld0;
        *(float4*)&buf[0][ob + LSTR]     = ld1;
        *(float4*)&buf[0][ob + 2 * LSTR] = ld2;
        *(float4*)&buf[0][ob + 3 * LSTR] = ld3;
        V[0] = istop ? ld1 : ld0;
        V[1] = ld1;
        V[2] = ld2;
        V[3] = isbot ? ld2 : ld3;
    }
    __syncthreads();

    auto step = [&](const float* __restrict__ cur, float* __restrict__ nxt, int t) {
        float4 U = *(const float4*)(cur + ub);
        float4 D = *(const float4*)(cur + db);
        float sl0 = cur[slo];            float sr0 = cur[sro];
        float sl1 = cur[slo + LSTR];     float sr1 = cur[sro + LSTR];
        float sl2 = cur[slo + 2 * LSTR]; float sr2 = cur[sro + 2 * LSTR];
        float sl3 = cur[slo + 3 * LSTR]; float sr3 = cur[sro + 3 * LSTR];

        // Up/down operand rows: interior rows from register carry.
        float4 Uop1 = istop ? U : V[0];   // row slot 1's up (LDS row 0 if replica-top)
        float4 Dop2 = isbot ? D : V[3];   // row slot 2's down (LDS row 95 if replica-bot)

        float4 NV0 = rowcell(V[0], U,    V[1], sl0, sr0, a2[0], k2[0], isl, isr);
        float4 NV1 = rowcell(V[1], Uop1, V[2], sl1, sr1, a2[1], k2[1], isl, isr);
        float4 NV2 = rowcell(V[2], V[1], Dop2, sl2, sr2, a2[2], k2[2], isl, isr);
        float4 NV3 = rowcell(V[3], V[2], D,    sl3, sr3, a2[3], k2[3], isl, isr);
        if (istop) NV0 = NV1;             // replica row
        if (isbot) NV3 = NV2;

        *(float4*)(nxt + ob)            = NV0;
        *(float4*)(nxt + ob + LSTR)     = NV1;
        *(float4*)(nxt + ob + 2 * LSTR) = NV2;
        *(float4*)(nxt + ob + 3 * LSTR) = NV3;

        if (core && t <= tmax) {
            float* slab = out + (long)(base + t - 1) * GNN;
            *(float4*)(slab + gbase)          = NV0;
            *(float4*)(slab + gbase + GN)     = NV1;
            *(float4*)(slab + gbase + 2 * GN) = NV2;
            *(float4*)(slab + gbase + 3 * GN) = NV3;
        }
        V[0] = NV0; V[1] = NV1; V[2] = NV2; V[3] = NV3;
        lds_barrier();
    };

    float* B0 = &buf[0][0];
    float* B1 = &buf[1][0];
    #pragma unroll 1
    for (int it = 0; it < KST / 2; ++it) {
        step(B0, B1, 2 * it + 1);
        step(B1, B0, 2 * it + 2);
    }
}

extern "C" void kernel_launch(void* const* d_in, const int* in_sizes, int n_in,
                              void* d_out, int out_size, void* d_ws, size_t ws_size,
                              hipStream_t stream) {
    const float* u0    = (const float*)d_in[0];
    const float* alpha = (const float*)d_in[1];
    const float* kappa = (const float*)d_in[2];
    float* out = (float*)d_out;

    dim3 grd(GN / TILE, GN / TILE, 1);   // 16x16 = 256 blocks = 1/CU

    bool use_ws = ws_size >= (size_t)2 * GNN * sizeof(float);

    if (use_ws) {
        float* a2map = (float*)d_ws;
        float* k2map = a2map + GNN;
        resize_maps_kernel<<<(GNN + 255) / 256, 256, 0, stream>>>(alpha, kappa, a2map, k2map);
        for (int b = 0; b < NOUT; b += KST) {
            const float* src = (b == 0) ? u0 : out + (long)(b - 1) * GNN;
            fused_steps_kernel<true><<<grd, NTHR, 0, stream>>>(src, a2map, k2map, out, b);
        }
    } else {
        for (int b = 0; b < NOUT; b += KST) {
            const float* src = (b == 0) ? u0 : out + (long)(b - 1) * GNN;
            fused_steps_kernel<false><<<grd, NTHR, 0, stream>>>(src, alpha, kappa, out, b);
        }
    }
}